// Round 10
// baseline (613.200 us; speedup 1.0000x reference)
//
#include <hip/hip_runtime.h>
#include <hip/hip_bf16.h>
#include <cstdint>

// ChannelAttention: x(2,512,64,64) f32, w_qkv(1536,512), w_proj(512,512), b_proj(512)
// Pipeline: xT(bf16) -> qkv GEMM -> flash attn (Q'=k*s, K'=v, V'=q) -> OT[b,h,d,n]
//           -> flat OT == scrambled Y matrix -> proj GEMM + bias -> d_out f32.
// R10: 8-wave k_attn with in-block m-split (waves w/w+4 share rows, split m-range;
//      fixed-base partials combine by simple addition). 8 waves/SIMD for latency
//      hiding (R9 post-mortem: latency-bound, TLP-starved). Reg V-dbuf reverted
//      (R9: neutral + VGPR evidence it was demoted anyway).

typedef __bf16 bf16_t;
typedef __bf16 bf16x8 __attribute__((ext_vector_type(8)));
typedef float f32x4 __attribute__((ext_vector_type(4)));
typedef unsigned int u32x4 __attribute__((ext_vector_type(4)));

#define DEVFN static __device__ __forceinline__
#define LOG2E 1.4426950408889634f

DEVFN f32x4 mfma16(bf16x8 a, bf16x8 b, f32x4 c) {
  return __builtin_amdgcn_mfma_f32_16x16x32_bf16(a, b, c, 0, 0, 0);
}
DEVFN unsigned bfbits(float x) { return (unsigned)__builtin_bit_cast(unsigned short, (bf16_t)x); }
DEVFN unsigned pack2(float lo, float hi) { return bfbits(lo) | (bfbits(hi) << 16); }

// ---------------- K0a: x (2,512,4096) f32 -> xT (8192,512) bf16 (transpose+cast) ----
__global__ __launch_bounds__(256) void k_transpose_x(const float* __restrict__ x,
                                                     bf16_t* __restrict__ xT) {
  __shared__ bf16_t tile[64][72];  // [c_local][n_local], padded
  int bid = blockIdx.x;            // 2 * 8 * 64 = 1024
  int ntile = bid & 63;
  int ctile = (bid >> 6) & 7;
  int b = bid >> 9;
  int n0 = ntile << 6, c0 = ctile << 6;
  int t = threadIdx.x;
  int ci = t >> 2, nc = (t & 3) << 4;
  const float4* src4 = reinterpret_cast<const float4*>(
      x + (size_t)(b * 512 + c0 + ci) * 4096 + n0 + nc);
#pragma unroll
  for (int j4 = 0; j4 < 4; ++j4) {
    float4 v = src4[j4];
    tile[ci][nc + j4 * 4 + 0] = (bf16_t)v.x;
    tile[ci][nc + j4 * 4 + 1] = (bf16_t)v.y;
    tile[ci][nc + j4 * 4 + 2] = (bf16_t)v.z;
    tile[ci][nc + j4 * 4 + 3] = (bf16_t)v.w;
  }
  __syncthreads();
  int ni = t & 63, cc = (t >> 6) << 4;  // each wave owns one 16-wide c-chunk
  unsigned ob[8];
#pragma unroll
  for (int j = 0; j < 8; ++j) {
    unsigned lo = (unsigned)__builtin_bit_cast(unsigned short, tile[cc + 2 * j][ni]);
    unsigned hi = (unsigned)__builtin_bit_cast(unsigned short, tile[cc + 2 * j + 1][ni]);
    ob[j] = lo | (hi << 16);
  }
  bf16_t* dst = xT + (size_t)(b * 4096 + n0 + ni) * 512 + c0 + cc;
  reinterpret_cast<u32x4*>(dst)[0] = *(u32x4*)&ob[0];
  reinterpret_cast<u32x4*>(dst)[1] = *(u32x4*)&ob[4];
}

// ---------------- K0b/K0c: f32 weights -> bf16 (optionally scale k-rows) -----------
// Scale for k-rows folds SCALE (1/8) AND log2(e) so attn can use exp2 directly.
__global__ __launch_bounds__(256) void k_convert_w(const float* __restrict__ w,
                                                   bf16_t* __restrict__ o, int do_scale) {
  int i = (blockIdx.x * 256 + threadIdx.x) * 4;
  float4 v = *reinterpret_cast<const float4*>(w + i);
  if (do_scale) {
    const float s = 0.125f * LOG2E;  // SCALE * log2e
    int m = i >> 9;  // row (512 cols per row)
    if (m >= 512 && m < 1024) { v.x *= s; v.y *= s; v.z *= s; v.w *= s; }
  }
  uint2 st; st.x = pack2(v.x, v.y); st.y = pack2(v.z, v.w);
  *reinterpret_cast<uint2*>(o + i) = st;
}

// ---------------- K1: qkv GEMM: M=8192 N=1536 K=512, bf16, direct-global frags -----
__global__ __launch_bounds__(256) void k_qkv_gemm(const bf16_t* __restrict__ xT,
                                                  const bf16_t* __restrict__ wq,
                                                  bf16_t* __restrict__ Qn,
                                                  bf16_t* __restrict__ Katt,
                                                  bf16_t* __restrict__ Vbuf) {
  int bid = blockIdx.x;  // 64 * 12
  int tm = bid / 12, tn = bid % 12;
  int wave = threadIdx.x >> 6, lane = threadIdx.x & 63;
  int n15 = lane & 15, g = lane >> 4;
  int wm = wave & 1, wn = wave >> 1;
  int row0 = tm * 128 + wm * 64;
  int col0 = tn * 128 + wn * 64;
  f32x4 acc[4][4] = {};
  const bf16_t* Ab = xT + (size_t)(row0 + n15) * 512 + g * 8;
  const bf16_t* Bb = wq + (size_t)(col0 + n15) * 512 + g * 8;
  for (int k = 0; k < 512; k += 32) {
    bf16x8 a[4], b[4];
#pragma unroll
    for (int mf = 0; mf < 4; ++mf) a[mf] = *reinterpret_cast<const bf16x8*>(Ab + mf * 16 * 512 + k);
#pragma unroll
    for (int nf = 0; nf < 4; ++nf) b[nf] = *reinterpret_cast<const bf16x8*>(Bb + nf * 16 * 512 + k);
#pragma unroll
    for (int mf = 0; mf < 4; ++mf)
#pragma unroll
      for (int nf = 0; nf < 4; ++nf) acc[mf][nf] = mfma16(a[mf], b[nf], acc[mf][nf]);
  }
  int t = col0 >> 9;  // 0:q 1:k(scaled via weights) 2:v — tile never crosses t
  bf16_t* dstbuf = (t == 0) ? Qn : (t == 1) ? Katt : Vbuf;
#pragma unroll
  for (int mf = 0; mf < 4; ++mf)
#pragma unroll
    for (int r = 0; r < 4; ++r) {
      int rgl = row0 + mf * 16 + g * 4 + r;
      int b_ = rgl >> 12, n = rgl & 4095;
#pragma unroll
      for (int nf = 0; nf < 4; ++nf) {
        int col = col0 + nf * 16 + n15;
        int h = (col >> 6) & 7, d = col & 63;
        dstbuf[(((size_t)(b_ * 8 + h) * 4096 + n) << 6) + d] = (bf16_t)acc[mf][nf][r];
      }
    }
}

// ---------------- K2: Qn[bh][n][d] -> QT[bh][d][n] (bf16 transpose) ----------------
__global__ __launch_bounds__(256) void k_transpose_q(const bf16_t* __restrict__ Qn,
                                                     bf16_t* __restrict__ QT) {
  __shared__ bf16_t tile[64][72];  // [n_local][d]
  int bid = blockIdx.x;            // 16 * 64
  int head = bid >> 6;
  int ntile = bid & 63;
  int n0 = ntile << 6;
  int t = threadIdx.x;
  int i = t >> 2, dc = (t & 3) << 4;
  const bf16_t* src = Qn + ((size_t)head * 4096 + n0 + i) * 64 + dc;
  *(u32x4*)&tile[i][dc] = reinterpret_cast<const u32x4*>(src)[0];
  *(u32x4*)&tile[i][dc + 8] = reinterpret_cast<const u32x4*>(src)[1];
  __syncthreads();
  int d = t & 63, nc2 = (t >> 6) << 4;
  unsigned ob[8];
#pragma unroll
  for (int j = 0; j < 8; ++j) {
    unsigned lo = (unsigned)__builtin_bit_cast(unsigned short, tile[nc2 + 2 * j][d]);
    unsigned hi = (unsigned)__builtin_bit_cast(unsigned short, tile[nc2 + 2 * j + 1][d]);
    ob[j] = lo | (hi << 16);
  }
  bf16_t* dst = QT + ((size_t)head * 64 + d) * 4096 + n0 + nc2;
  reinterpret_cast<u32x4*>(dst)[0] = *(u32x4*)&ob[0];
  reinterpret_cast<u32x4*>(dst)[1] = *(u32x4*)&ob[4];
}

// ---------------- K3: flash attention, fixed-base softmax, 8-wave m-split -----------
// Roles: Q'=Katt (k*SCALE*log2e), K'=Vbuf (v), V'=QT (q, transposed). Out OT[bh][d][n].
// Waves w (mhalf=0) and w+4 (mhalf=1) handle the same 16 n-rows, disjoint m-halves.
// Fixed-base softmax => partials combine by addition: O = (o0+o1)/(l0+l1).
__global__ __launch_bounds__(512, 8) void k_attn(const bf16_t* __restrict__ Katt,
                                                 const bf16_t* __restrict__ Vbuf,
                                                 const bf16_t* __restrict__ QT,
                                                 bf16_t* __restrict__ OT) {
  __shared__ float olds[4][64][16];   // [wrow][lane][4*db+r] upper-half o partials (16KB)
  __shared__ float llds[4][16];       // upper-half l partials
  __shared__ bf16_t tlds[4][16][72];  // transpose staging (9KB)
  int bid = blockIdx.x;   // 1024
  int head = bid & 15;    // XCD-friendly: per-XCD KV working set is L2-fit
  int ntile = bid >> 4;   // 0..63
  int tid = threadIdx.x;
  int wave = tid >> 6, lane = tid & 63;
  int wrow = wave & 3;    // 16-row group within the 64-row tile
  int mhalf = wave >> 2;  // m-range half: 0 -> [0,2048), 1 -> [2048,4096)
  int n15 = lane & 15, g = lane >> 4;
  int nrow0 = ntile * 64 + wrow * 16;

  const bf16_t* Kp = Katt + ((size_t)head * 4096 + nrow0 + n15) * 64 + g * 8;
  bf16x8 kf0 = *reinterpret_cast<const bf16x8*>(Kp);
  bf16x8 kf1 = *reinterpret_cast<const bf16x8*>(Kp + 32);
  const bf16_t* Vb = Vbuf + ((size_t)head * 4096 + n15) * 64 + g * 8;
  const bf16_t* Qt = QT + ((size_t)head * 64 + n15) * 4096 + g * 8;

  f32x4 o[4] = {};
  float lacc = 0.f;
  bool hi_g = (g >= 2);
  int srcA = n15 + 16 * ((2 * g) & 3);
  int srcB = n15 + 16 * ((2 * g + 1) & 3);

  int mbeg = mhalf << 11;  // 0 or 2048
  for (int m0 = mbeg; m0 < mbeg + 2048; m0 += 64) {
    // S^T tile: lane holds S^T[m = g*4+r (+16f), n = n15]
    f32x4 p[4];
#pragma unroll
    for (int f = 0; f < 4; ++f) {
      const bf16_t* vp = Vb + (size_t)(m0 + f * 16) * 64;
      bf16x8 av0 = *reinterpret_cast<const bf16x8*>(vp);
      bf16x8 av1 = *reinterpret_cast<const bf16x8*>(vp + 32);
      f32x4 s = {};
      s = mfma16(av0, kf0, s);
      s = mfma16(av1, kf1, s);
      p[f] = s;
    }
    // fixed-base softmax: p = exp2(s) directly, accumulate l per-lane
    unsigned pk[4][2];
#pragma unroll
    for (int f = 0; f < 4; ++f) {
#pragma unroll
      for (int r = 0; r < 4; ++r) {
        float e = __builtin_amdgcn_exp2f(p[f][r]);
        p[f][r] = e;
        lacc += e;
      }
      pk[f][0] = pack2(p[f][0], p[f][1]);
      pk[f][1] = pack2(p[f][2], p[f][3]);
    }
    // redistribute P into PV A-fragments
    bf16x8 aP[2];
#pragma unroll
    for (int kk = 0; kk < 2; ++kk) {
      unsigned t00a = (unsigned)__shfl((int)pk[2 * kk + 0][0], srcA);
      unsigned t01a = (unsigned)__shfl((int)pk[2 * kk + 0][1], srcA);
      unsigned t10a = (unsigned)__shfl((int)pk[2 * kk + 1][0], srcA);
      unsigned t11a = (unsigned)__shfl((int)pk[2 * kk + 1][1], srcA);
      unsigned t00b = (unsigned)__shfl((int)pk[2 * kk + 0][0], srcB);
      unsigned t01b = (unsigned)__shfl((int)pk[2 * kk + 0][1], srcB);
      unsigned t10b = (unsigned)__shfl((int)pk[2 * kk + 1][0], srcB);
      unsigned t11b = (unsigned)__shfl((int)pk[2 * kk + 1][1], srcB);
      u32x4 uu;
      uu[0] = hi_g ? t10a : t00a;
      uu[1] = hi_g ? t11a : t01a;
      uu[2] = hi_g ? t10b : t00b;
      uu[3] = hi_g ? t11b : t01b;
      aP[kk] = __builtin_bit_cast(bf16x8, uu);
    }
    // PV: o[n, d] += P @ V'  (per-db bq loads keep peak VGPR under the 64 cap)
#pragma unroll
    for (int db = 0; db < 4; ++db) {
      const bf16_t* qp = Qt + (size_t)db * 16 * 4096 + m0;
      bf16x8 bq0 = *reinterpret_cast<const bf16x8*>(qp);
      bf16x8 bq1 = *reinterpret_cast<const bf16x8*>(qp + 32);
      o[db] = mfma16(aP[0], bq0, o[db]);
      o[db] = mfma16(aP[1], bq1, o[db]);
    }
  }
  // per-wave l reduce: after xor 16/32, all 4 g-lanes of a column hold l[n15]
  lacc += __shfl_xor(lacc, 16);
  lacc += __shfl_xor(lacc, 32);

  // cross-half combine: upper waves publish partials, lower waves merge
  if (mhalf == 1) {
#pragma unroll
    for (int db = 0; db < 4; ++db)
      *reinterpret_cast<f32x4*>(&olds[wrow][lane][db * 4]) = o[db];
    if (g == 0) llds[wrow][n15] = lacc;
  }
  __syncthreads();
  if (mhalf == 0) {
#pragma unroll
    for (int db = 0; db < 4; ++db)
      o[db] += *reinterpret_cast<const f32x4*>(&olds[wrow][lane][db * 4]);
    lacc += llds[wrow][n15];
    // normalize + stage transpose (o[db][r] = O[n=g*4+r][d=n15+16*db])
#pragma unroll
    for (int r = 0; r < 4; ++r) {
      float l_r = __shfl(lacc, (g << 2) | r);
      float inv = 1.0f / l_r;
#pragma unroll
      for (int db = 0; db < 4; ++db)
        tlds[wrow][g * 4 + r][n15 + 16 * db] = (bf16_t)(o[db][r] * inv);
    }
  }
  __syncthreads();
  if (mhalf == 0) {
    int d = lane;
    unsigned ob[8];
#pragma unroll
    for (int j = 0; j < 8; ++j) {
      unsigned lo = (unsigned)__builtin_bit_cast(unsigned short, tlds[wrow][2 * j][d]);
      unsigned hi = (unsigned)__builtin_bit_cast(unsigned short, tlds[wrow][2 * j + 1][d]);
      ob[j] = lo | (hi << 16);
    }
    bf16_t* dst = OT + ((size_t)head * 64 + d) * 4096 + (size_t)ntile * 64 + wrow * 16;
    reinterpret_cast<u32x4*>(dst)[0] = *(u32x4*)&ob[0];
    reinterpret_cast<u32x4*>(dst)[1] = *(u32x4*)&ob[4];
  }
}

// ---------------- K4: proj GEMM: out = Y @ w_proj^T + b, M=8192 N=512 K=512 --------
__global__ __launch_bounds__(256) void k_proj_gemm(const bf16_t* __restrict__ Y,
                                                   const bf16_t* __restrict__ wp,
                                                   const float* __restrict__ bp,
                                                   float* __restrict__ out) {
  int bid = blockIdx.x;  // 64*4
  int tm = bid >> 2, tn = bid & 3;
  int wave = threadIdx.x >> 6, lane = threadIdx.x & 63;
  int n15 = lane & 15, g = lane >> 4;
  int wm = wave & 1, wn = wave >> 1;
  int row0 = tm * 128 + wm * 64;
  int col0 = tn * 128 + wn * 64;
  f32x4 acc[4][4] = {};
  const bf16_t* Ab = Y + (size_t)(row0 + n15) * 512 + g * 8;
  const bf16_t* Bb = wp + (size_t)(col0 + n15) * 512 + g * 8;
  for (int k = 0; k < 512; k += 32) {
    bf16x8 a[4], b[4];
#pragma unroll
    for (int mf = 0; mf < 4; ++mf) a[mf] = *reinterpret_cast<const bf16x8*>(Ab + mf * 16 * 512 + k);
#pragma unroll
    for (int nf = 0; nf < 4; ++nf) b[nf] = *reinterpret_cast<const bf16x8*>(Bb + nf * 16 * 512 + k);
#pragma unroll
    for (int mf = 0; mf < 4; ++mf)
#pragma unroll
      for (int nf = 0; nf < 4; ++nf) acc[mf][nf] = mfma16(a[mf], b[nf], acc[mf][nf]);
  }
  float bias[4];
#pragma unroll
  for (int nf = 0; nf < 4; ++nf) bias[nf] = bp[col0 + nf * 16 + n15];
#pragma unroll
  for (int mf = 0; mf < 4; ++mf)
#pragma unroll
    for (int r = 0; r < 4; ++r) {
      int rgl = row0 + mf * 16 + g * 4 + r;
#pragma unroll
      for (int nf = 0; nf < 4; ++nf) {
        int col = col0 + nf * 16 + n15;
        out[(size_t)rgl * 512 + col] = acc[mf][nf][r] + bias[nf];
      }
    }
}

// ---------------- launch -------------------------------------------------------------
extern "C" void kernel_launch(void* const* d_in, const int* in_sizes, int n_in,
                              void* d_out, int out_size, void* d_ws, size_t ws_size,
                              hipStream_t stream) {
  const float* x      = (const float*)d_in[0];
  const float* w_qkv  = (const float*)d_in[1];
  const float* w_proj = (const float*)d_in[2];
  const float* b_proj = (const float*)d_in[3];
  float* out = (float*)d_out;
  char* ws = (char*)d_ws;

  // workspace map (bytes), 34 MB total:
  //   [0, 8M)        xT   (dead after K1)  -> reused as QT by K2
  //   [8M, 9.5M)     wqkv
  //   [9.5M, 10M)    wproj
  //   [10M, 18M)     Qn   (dead after K2)  -> reused as OT by K3
  //   [18M, 26M)     Katt
  //   [26M, 34M)     Vbuf
  bf16_t* xT    = (bf16_t*)(ws + 0);
  bf16_t* wqkv  = (bf16_t*)(ws + 8388608);
  bf16_t* wproj = (bf16_t*)(ws + 9961472);
  bf16_t* Qn    = (bf16_t*)(ws + 10485760);
  bf16_t* Katt  = (bf16_t*)(ws + 18874368);
  bf16_t* Vbuf  = (bf16_t*)(ws + 27262976);
  bf16_t* QT    = (bf16_t*)(ws + 0);          // over xT
  bf16_t* OT    = (bf16_t*)(ws + 10485760);   // over Qn

  k_transpose_x<<<dim3(1024), dim3(256), 0, stream>>>(x, xT);
  k_convert_w<<<dim3(768), dim3(256), 0, stream>>>(w_qkv, wqkv, 1);
  k_convert_w<<<dim3(256), dim3(256), 0, stream>>>(w_proj, wproj, 0);
  k_qkv_gemm<<<dim3(768), dim3(256), 0, stream>>>(xT, wqkv, Qn, Katt, Vbuf);
  k_transpose_q<<<dim3(1024), dim3(256), 0, stream>>>(Qn, QT);
  k_attn<<<dim3(1024), dim3(512), 0, stream>>>(Katt, Vbuf, QT, OT);
  k_proj_gemm<<<dim3(256), dim3(256), 0, stream>>>(OT, wproj, b_proj, out);
}

// Round 11
// 265.536 us; speedup vs baseline: 2.3093x; 2.3093x over previous
//
#include <hip/hip_runtime.h>
#include <hip/hip_bf16.h>
#include <cstdint>

// ChannelAttention: x(2,512,64,64) f32, w_qkv(1536,512), w_proj(512,512), b_proj(512)
// Pipeline: xT(bf16) -> qkv GEMM -> flash attn (Q'=k*s, K'=v, V'=q) -> OT[b,h,d,n]
//           -> flat OT == scrambled Y matrix -> proj GEMM + bias -> d_out f32.
// R11: k_attn restructured around block-cooperative LDS staging of the shared V/Q
//      tiles (R9/R10 post-mortem: time invariant to occupancy & VALU count =>
//      per-CU L2-latency/MSHR bound on redundant per-wave streams). 8 waves own
//      128 distinct n-rows/block; V+Q tiles staged once per block per m-step,
//      double-buffered, XOR-swizzled; global loads issued early (T14).

typedef __bf16 bf16_t;
typedef __bf16 bf16x8 __attribute__((ext_vector_type(8)));
typedef float f32x4 __attribute__((ext_vector_type(4)));
typedef unsigned int u32x4 __attribute__((ext_vector_type(4)));

#define DEVFN static __device__ __forceinline__
#define LOG2E 1.4426950408889634f

DEVFN f32x4 mfma16(bf16x8 a, bf16x8 b, f32x4 c) {
  return __builtin_amdgcn_mfma_f32_16x16x32_bf16(a, b, c, 0, 0, 0);
}
DEVFN unsigned bfbits(float x) { return (unsigned)__builtin_bit_cast(unsigned short, (bf16_t)x); }
DEVFN unsigned pack2(float lo, float hi) { return bfbits(lo) | (bfbits(hi) << 16); }

// ---------------- K0a: x (2,512,4096) f32 -> xT (8192,512) bf16 (transpose+cast) ----
__global__ __launch_bounds__(256) void k_transpose_x(const float* __restrict__ x,
                                                     bf16_t* __restrict__ xT) {
  __shared__ bf16_t tile[64][72];  // [c_local][n_local], padded
  int bid = blockIdx.x;            // 2 * 8 * 64 = 1024
  int ntile = bid & 63;
  int ctile = (bid >> 6) & 7;
  int b = bid >> 9;
  int n0 = ntile << 6, c0 = ctile << 6;
  int t = threadIdx.x;
  int ci = t >> 2, nc = (t & 3) << 4;
  const float4* src4 = reinterpret_cast<const float4*>(
      x + (size_t)(b * 512 + c0 + ci) * 4096 + n0 + nc);
#pragma unroll
  for (int j4 = 0; j4 < 4; ++j4) {
    float4 v = src4[j4];
    tile[ci][nc + j4 * 4 + 0] = (bf16_t)v.x;
    tile[ci][nc + j4 * 4 + 1] = (bf16_t)v.y;
    tile[ci][nc + j4 * 4 + 2] = (bf16_t)v.z;
    tile[ci][nc + j4 * 4 + 3] = (bf16_t)v.w;
  }
  __syncthreads();
  int ni = t & 63, cc = (t >> 6) << 4;  // each wave owns one 16-wide c-chunk
  unsigned ob[8];
#pragma unroll
  for (int j = 0; j < 8; ++j) {
    unsigned lo = (unsigned)__builtin_bit_cast(unsigned short, tile[cc + 2 * j][ni]);
    unsigned hi = (unsigned)__builtin_bit_cast(unsigned short, tile[cc + 2 * j + 1][ni]);
    ob[j] = lo | (hi << 16);
  }
  bf16_t* dst = xT + (size_t)(b * 4096 + n0 + ni) * 512 + c0 + cc;
  reinterpret_cast<u32x4*>(dst)[0] = *(u32x4*)&ob[0];
  reinterpret_cast<u32x4*>(dst)[1] = *(u32x4*)&ob[4];
}

// ---------------- K0b/K0c: f32 weights -> bf16 (optionally scale k-rows) -----------
// Scale for k-rows folds SCALE (1/8) AND log2(e) so attn can use exp2 directly.
__global__ __launch_bounds__(256) void k_convert_w(const float* __restrict__ w,
                                                   bf16_t* __restrict__ o, int do_scale) {
  int i = (blockIdx.x * 256 + threadIdx.x) * 4;
  float4 v = *reinterpret_cast<const float4*>(w + i);
  if (do_scale) {
    const float s = 0.125f * LOG2E;  // SCALE * log2e
    int m = i >> 9;  // row (512 cols per row)
    if (m >= 512 && m < 1024) { v.x *= s; v.y *= s; v.z *= s; v.w *= s; }
  }
  uint2 st; st.x = pack2(v.x, v.y); st.y = pack2(v.z, v.w);
  *reinterpret_cast<uint2*>(o + i) = st;
}

// ---------------- K1: qkv GEMM: M=8192 N=1536 K=512, bf16, direct-global frags -----
__global__ __launch_bounds__(256) void k_qkv_gemm(const bf16_t* __restrict__ xT,
                                                  const bf16_t* __restrict__ wq,
                                                  bf16_t* __restrict__ Qn,
                                                  bf16_t* __restrict__ Katt,
                                                  bf16_t* __restrict__ Vbuf) {
  int bid = blockIdx.x;  // 64 * 12
  int tm = bid / 12, tn = bid % 12;
  int wave = threadIdx.x >> 6, lane = threadIdx.x & 63;
  int n15 = lane & 15, g = lane >> 4;
  int wm = wave & 1, wn = wave >> 1;
  int row0 = tm * 128 + wm * 64;
  int col0 = tn * 128 + wn * 64;
  f32x4 acc[4][4] = {};
  const bf16_t* Ab = xT + (size_t)(row0 + n15) * 512 + g * 8;
  const bf16_t* Bb = wq + (size_t)(col0 + n15) * 512 + g * 8;
  for (int k = 0; k < 512; k += 32) {
    bf16x8 a[4], b[4];
#pragma unroll
    for (int mf = 0; mf < 4; ++mf) a[mf] = *reinterpret_cast<const bf16x8*>(Ab + mf * 16 * 512 + k);
#pragma unroll
    for (int nf = 0; nf < 4; ++nf) b[nf] = *reinterpret_cast<const bf16x8*>(Bb + nf * 16 * 512 + k);
#pragma unroll
    for (int mf = 0; mf < 4; ++mf)
#pragma unroll
      for (int nf = 0; nf < 4; ++nf) acc[mf][nf] = mfma16(a[mf], b[nf], acc[mf][nf]);
  }
  int t = col0 >> 9;  // 0:q 1:k(scaled via weights) 2:v — tile never crosses t
  bf16_t* dstbuf = (t == 0) ? Qn : (t == 1) ? Katt : Vbuf;
#pragma unroll
  for (int mf = 0; mf < 4; ++mf)
#pragma unroll
    for (int r = 0; r < 4; ++r) {
      int rgl = row0 + mf * 16 + g * 4 + r;
      int b_ = rgl >> 12, n = rgl & 4095;
#pragma unroll
      for (int nf = 0; nf < 4; ++nf) {
        int col = col0 + nf * 16 + n15;
        int h = (col >> 6) & 7, d = col & 63;
        dstbuf[(((size_t)(b_ * 8 + h) * 4096 + n) << 6) + d] = (bf16_t)acc[mf][nf][r];
      }
    }
}

// ---------------- K2: Qn[bh][n][d] -> QT[bh][d][n] (bf16 transpose) ----------------
__global__ __launch_bounds__(256) void k_transpose_q(const bf16_t* __restrict__ Qn,
                                                     bf16_t* __restrict__ QT) {
  __shared__ bf16_t tile[64][72];  // [n_local][d]
  int bid = blockIdx.x;            // 16 * 64
  int head = bid >> 6;
  int ntile = bid & 63;
  int n0 = ntile << 6;
  int t = threadIdx.x;
  int i = t >> 2, dc = (t & 3) << 4;
  const bf16_t* src = Qn + ((size_t)head * 4096 + n0 + i) * 64 + dc;
  *(u32x4*)&tile[i][dc] = reinterpret_cast<const u32x4*>(src)[0];
  *(u32x4*)&tile[i][dc + 8] = reinterpret_cast<const u32x4*>(src)[1];
  __syncthreads();
  int d = t & 63, nc2 = (t >> 6) << 4;
  unsigned ob[8];
#pragma unroll
  for (int j = 0; j < 8; ++j) {
    unsigned lo = (unsigned)__builtin_bit_cast(unsigned short, tile[nc2 + 2 * j][d]);
    unsigned hi = (unsigned)__builtin_bit_cast(unsigned short, tile[nc2 + 2 * j + 1][d]);
    ob[j] = lo | (hi << 16);
  }
  bf16_t* dst = QT + ((size_t)head * 64 + d) * 4096 + n0 + nc2;
  reinterpret_cast<u32x4*>(dst)[0] = *(u32x4*)&ob[0];
  reinterpret_cast<u32x4*>(dst)[1] = *(u32x4*)&ob[4];
}

// ---------------- K3: flash attention, LDS-staged V/Q, fixed-base softmax -----------
// Roles: Q'=Katt (k*SCALE*log2e), K'=Vbuf (v), V'=QT (q, transposed). Out OT[bh][d][n].
// 8 waves x 16 distinct n-rows = 128 rows/block; per m-step the block stages the
// shared V-tile (64x64) and Q-tile (64x64) into LDS once (reg-staged, issue-early /
// write-late, double-buffered, XOR-swizzled granules for conflict-free ds_read_b128).
__global__ __launch_bounds__(512, 4) void k_attn(const bf16_t* __restrict__ Katt,
                                                 const bf16_t* __restrict__ Vbuf,
                                                 const bf16_t* __restrict__ QT,
                                                 bf16_t* __restrict__ OT) {
  __shared__ bf16_t Vt[2][4096];       // [buf][m_row*64 + d]  (granule-swizzled) 16KB
  __shared__ bf16_t Qs[2][4096];       // [buf][d_row*64 + m]  (granule-swizzled) 16KB
  __shared__ bf16_t tlds[8][16][72];   // transpose staging, 18KB
  int bid = blockIdx.x;   // 512
  int head = bid & 15;    // XCD-friendly: heads {x, x+8} per XCD, ~3MB L2 set
  int ntile = bid >> 4;   // 0..31
  int tid = threadIdx.x;
  int wave = tid >> 6, lane = tid & 63;
  int n15 = lane & 15, g = lane >> 4;
  int nrow0 = ntile * 128 + wave * 16;

  // K fragments: per-wave, loaded once from global
  const bf16_t* Kp = Katt + ((size_t)head * 4096 + nrow0 + n15) * 64 + g * 8;
  bf16x8 kf0 = *reinterpret_cast<const bf16x8*>(Kp);
  bf16x8 kf1 = *reinterpret_cast<const bf16x8*>(Kp + 32);

  // staging map: thread -> one 16B granule of V-tile and one of Q-tile
  int vrow = tid >> 3, vg = tid & 7;                  // row 0..63, granule 0..7
  int soff = vrow * 64 + ((vg ^ (vrow & 7)) << 3);    // swizzled LDS elem offset
  const bf16_t* VgB = Vbuf + ((size_t)head * 4096 + vrow) * 64 + vg * 8;
  const bf16_t* QgB = QT + ((size_t)head * 64 + vrow) * 4096 + vg * 8;

  // prologue: stage tile 0
  u32x4 vreg = *reinterpret_cast<const u32x4*>(VgB);
  u32x4 qreg = *reinterpret_cast<const u32x4*>(QgB);
  *reinterpret_cast<u32x4*>(&Vt[0][soff]) = vreg;
  *reinterpret_cast<u32x4*>(&Qs[0][soff]) = qreg;
  __syncthreads();

  f32x4 o[4] = {};
  float lacc = 0.f;
  bool hi_g = (g >= 2);
  int srcA = n15 + 16 * ((2 * g) & 3);
  int srcB = n15 + 16 * ((2 * g + 1) & 3);
  int sw = n15 & 7;
  int voff0 = n15 * 64 + (((g) ^ sw) << 3);       // frag granule g   (swizzled)
  int voff1 = n15 * 64 + (((g + 4) ^ sw) << 3);   // frag granule g+4 (swizzled)

  int cur = 0;
  for (int it = 0; it < 64; ++it) {
    // issue next-tile global loads early; latency hides under this tile's compute
    if (it < 63) {
      vreg = *reinterpret_cast<const u32x4*>(VgB + (size_t)(it + 1) * 4096);
      qreg = *reinterpret_cast<const u32x4*>(QgB + (it + 1) * 64);
    }
    const bf16_t* Vl = Vt[cur];
    const bf16_t* Ql = Qs[cur];
    // S^T tile: lane holds S^T[m = g*4+r (+16f), n = n15]
    f32x4 p[4];
#pragma unroll
    for (int f = 0; f < 4; ++f) {
      bf16x8 av0 = *reinterpret_cast<const bf16x8*>(Vl + f * 1024 + voff0);
      bf16x8 av1 = *reinterpret_cast<const bf16x8*>(Vl + f * 1024 + voff1);
      f32x4 s = {};
      s = mfma16(av0, kf0, s);
      s = mfma16(av1, kf1, s);
      p[f] = s;
    }
    // fixed-base softmax: p = exp2(s), accumulate l per-lane
    unsigned pk[4][2];
#pragma unroll
    for (int f = 0; f < 4; ++f) {
#pragma unroll
      for (int r = 0; r < 4; ++r) {
        float e = __builtin_amdgcn_exp2f(p[f][r]);
        p[f][r] = e;
        lacc += e;
      }
      pk[f][0] = pack2(p[f][0], p[f][1]);
      pk[f][1] = pack2(p[f][2], p[f][3]);
    }
    // redistribute P into PV A-fragments
    bf16x8 aP[2];
#pragma unroll
    for (int kk = 0; kk < 2; ++kk) {
      unsigned t00a = (unsigned)__shfl((int)pk[2 * kk + 0][0], srcA);
      unsigned t01a = (unsigned)__shfl((int)pk[2 * kk + 0][1], srcA);
      unsigned t10a = (unsigned)__shfl((int)pk[2 * kk + 1][0], srcA);
      unsigned t11a = (unsigned)__shfl((int)pk[2 * kk + 1][1], srcA);
      unsigned t00b = (unsigned)__shfl((int)pk[2 * kk + 0][0], srcB);
      unsigned t01b = (unsigned)__shfl((int)pk[2 * kk + 0][1], srcB);
      unsigned t10b = (unsigned)__shfl((int)pk[2 * kk + 1][0], srcB);
      unsigned t11b = (unsigned)__shfl((int)pk[2 * kk + 1][1], srcB);
      u32x4 uu;
      uu[0] = hi_g ? t10a : t00a;
      uu[1] = hi_g ? t11a : t01a;
      uu[2] = hi_g ? t10b : t00b;
      uu[3] = hi_g ? t11b : t01b;
      aP[kk] = __builtin_bit_cast(bf16x8, uu);
    }
    // PV: o[n, d] += P @ V'   (B-frags from staged Q tile)
#pragma unroll
    for (int db = 0; db < 4; ++db) {
      bf16x8 bq0 = *reinterpret_cast<const bf16x8*>(Ql + db * 1024 + voff0);
      bf16x8 bq1 = *reinterpret_cast<const bf16x8*>(Ql + db * 1024 + voff1);
      o[db] = mfma16(aP[0], bq0, o[db]);
      o[db] = mfma16(aP[1], bq1, o[db]);
    }
    // write next tile into the other buffer; barrier publishes it
    if (it < 63) {
      *reinterpret_cast<u32x4*>(&Vt[cur ^ 1][soff]) = vreg;
      *reinterpret_cast<u32x4*>(&Qs[cur ^ 1][soff]) = qreg;
    }
    __syncthreads();
    cur ^= 1;
  }

  // final l reduce (once) + normalize + transpose via LDS, store OT coalesced
  lacc += __shfl_xor(lacc, 16);
  lacc += __shfl_xor(lacc, 32);
#pragma unroll
  for (int r = 0; r < 4; ++r) {
    float l_r = __shfl(lacc, (g << 2) | r);
    float inv = 1.0f / l_r;
#pragma unroll
    for (int db = 0; db < 4; ++db)
      tlds[wave][g * 4 + r][n15 + 16 * db] = (bf16_t)(o[db][r] * inv);
  }
  __syncthreads();
  {
    int d = lane;
    unsigned ob[8];
#pragma unroll
    for (int j = 0; j < 8; ++j) {
      unsigned lo = (unsigned)__builtin_bit_cast(unsigned short, tlds[wave][2 * j][d]);
      unsigned hi = (unsigned)__builtin_bit_cast(unsigned short, tlds[wave][2 * j + 1][d]);
      ob[j] = lo | (hi << 16);
    }
    bf16_t* dst = OT + ((size_t)head * 64 + d) * 4096 + (size_t)ntile * 128 + wave * 16;
    reinterpret_cast<u32x4*>(dst)[0] = *(u32x4*)&ob[0];
    reinterpret_cast<u32x4*>(dst)[1] = *(u32x4*)&ob[4];
  }
}

// ---------------- K4: proj GEMM: out = Y @ w_proj^T + b, M=8192 N=512 K=512 --------
__global__ __launch_bounds__(256) void k_proj_gemm(const bf16_t* __restrict__ Y,
                                                   const bf16_t* __restrict__ wp,
                                                   const float* __restrict__ bp,
                                                   float* __restrict__ out) {
  int bid = blockIdx.x;  // 64*4
  int tm = bid >> 2, tn = bid & 3;
  int wave = threadIdx.x >> 6, lane = threadIdx.x & 63;
  int n15 = lane & 15, g = lane >> 4;
  int wm = wave & 1, wn = wave >> 1;
  int row0 = tm * 128 + wm * 64;
  int col0 = tn * 128 + wn * 64;
  f32x4 acc[4][4] = {};
  const bf16_t* Ab = Y + (size_t)(row0 + n15) * 512 + g * 8;
  const bf16_t* Bb = wp + (size_t)(col0 + n15) * 512 + g * 8;
  for (int k = 0; k < 512; k += 32) {
    bf16x8 a[4], b[4];
#pragma unroll
    for (int mf = 0; mf < 4; ++mf) a[mf] = *reinterpret_cast<const bf16x8*>(Ab + mf * 16 * 512 + k);
#pragma unroll
    for (int nf = 0; nf < 4; ++nf) b[nf] = *reinterpret_cast<const bf16x8*>(Bb + nf * 16 * 512 + k);
#pragma unroll
    for (int mf = 0; mf < 4; ++mf)
#pragma unroll
      for (int nf = 0; nf < 4; ++nf) acc[mf][nf] = mfma16(a[mf], b[nf], acc[mf][nf]);
  }
  float bias[4];
#pragma unroll
  for (int nf = 0; nf < 4; ++nf) bias[nf] = bp[col0 + nf * 16 + n15];
#pragma unroll
  for (int mf = 0; mf < 4; ++mf)
#pragma unroll
    for (int r = 0; r < 4; ++r) {
      int rgl = row0 + mf * 16 + g * 4 + r;
#pragma unroll
      for (int nf = 0; nf < 4; ++nf) {
        int col = col0 + nf * 16 + n15;
        out[(size_t)rgl * 512 + col] = acc[mf][nf][r] + bias[nf];
      }
    }
}

// ---------------- launch -------------------------------------------------------------
extern "C" void kernel_launch(void* const* d_in, const int* in_sizes, int n_in,
                              void* d_out, int out_size, void* d_ws, size_t ws_size,
                              hipStream_t stream) {
  const float* x      = (const float*)d_in[0];
  const float* w_qkv  = (const float*)d_in[1];
  const float* w_proj = (const float*)d_in[2];
  const float* b_proj = (const float*)d_in[3];
  float* out = (float*)d_out;
  char* ws = (char*)d_ws;

  // workspace map (bytes), 34 MB total:
  //   [0, 8M)        xT   (dead after K1)  -> reused as QT by K2
  //   [8M, 9.5M)     wqkv
  //   [9.5M, 10M)    wproj
  //   [10M, 18M)     Qn   (dead after K2)  -> reused as OT by K3
  //   [18M, 26M)     Katt
  //   [26M, 34M)     Vbuf
  bf16_t* xT    = (bf16_t*)(ws + 0);
  bf16_t* wqkv  = (bf16_t*)(ws + 8388608);
  bf16_t* wproj = (bf16_t*)(ws + 9961472);
  bf16_t* Qn    = (bf16_t*)(ws + 10485760);
  bf16_t* Katt  = (bf16_t*)(ws + 18874368);
  bf16_t* Vbuf  = (bf16_t*)(ws + 27262976);
  bf16_t* QT    = (bf16_t*)(ws + 0);          // over xT
  bf16_t* OT    = (bf16_t*)(ws + 10485760);   // over Qn

  k_transpose_x<<<dim3(1024), dim3(256), 0, stream>>>(x, xT);
  k_convert_w<<<dim3(768), dim3(256), 0, stream>>>(w_qkv, wqkv, 1);
  k_convert_w<<<dim3(256), dim3(256), 0, stream>>>(w_proj, wproj, 0);
  k_qkv_gemm<<<dim3(768), dim3(256), 0, stream>>>(xT, wqkv, Qn, Katt, Vbuf);
  k_transpose_q<<<dim3(1024), dim3(256), 0, stream>>>(Qn, QT);
  k_attn<<<dim3(512), dim3(512), 0, stream>>>(Katt, Vbuf, QT, OT);
  k_proj_gemm<<<dim3(256), dim3(256), 0, stream>>>(OT, wproj, b_proj, out);
}

// Round 13
// 239.097 us; speedup vs baseline: 2.5647x; 1.1106x over previous
//
#include <hip/hip_runtime.h>
#include <hip/hip_bf16.h>
#include <cstdint>

// ChannelAttention: x(2,512,64,64) f32, w_qkv(1536,512), w_proj(512,512), b_proj(512)
// Pipeline: xT(bf16) -> qkv GEMM -> flash attn (Q'=k*s, K'=v, V'=q) -> OT[b,h,d,n]
//           -> flat OT == scrambled Y matrix -> proj GEMM + bias -> d_out f32.
// R12/R13: both GEMMs rebuilt with the R11-proven pattern — block-cooperative LDS
//      staging (reg-staged, issue-early/write-late, double-buffered, XOR-swizzled
//      granules). Kills redundant per-wave L2 streams (the R10/R11-confirmed
//      MSHR bottleneck). k_attn frozen at the R11 winner.

typedef __bf16 bf16_t;
typedef __bf16 bf16x8 __attribute__((ext_vector_type(8)));
typedef float f32x4 __attribute__((ext_vector_type(4)));
typedef unsigned int u32x4 __attribute__((ext_vector_type(4)));

#define DEVFN static __device__ __forceinline__
#define LOG2E 1.4426950408889634f

DEVFN f32x4 mfma16(bf16x8 a, bf16x8 b, f32x4 c) {
  return __builtin_amdgcn_mfma_f32_16x16x32_bf16(a, b, c, 0, 0, 0);
}
DEVFN unsigned bfbits(float x) { return (unsigned)__builtin_bit_cast(unsigned short, (bf16_t)x); }
DEVFN unsigned pack2(float lo, float hi) { return bfbits(lo) | (bfbits(hi) << 16); }

// ---------------- K0a: x (2,512,4096) f32 -> xT (8192,512) bf16 (transpose+cast) ----
__global__ __launch_bounds__(256) void k_transpose_x(const float* __restrict__ x,
                                                     bf16_t* __restrict__ xT) {
  __shared__ bf16_t tile[64][72];  // [c_local][n_local], padded
  int bid = blockIdx.x;            // 2 * 8 * 64 = 1024
  int ntile = bid & 63;
  int ctile = (bid >> 6) & 7;
  int b = bid >> 9;
  int n0 = ntile << 6, c0 = ctile << 6;
  int t = threadIdx.x;
  int ci = t >> 2, nc = (t & 3) << 4;
  const float4* src4 = reinterpret_cast<const float4*>(
      x + (size_t)(b * 512 + c0 + ci) * 4096 + n0 + nc);
#pragma unroll
  for (int j4 = 0; j4 < 4; ++j4) {
    float4 v = src4[j4];
    tile[ci][nc + j4 * 4 + 0] = (bf16_t)v.x;
    tile[ci][nc + j4 * 4 + 1] = (bf16_t)v.y;
    tile[ci][nc + j4 * 4 + 2] = (bf16_t)v.z;
    tile[ci][nc + j4 * 4 + 3] = (bf16_t)v.w;
  }
  __syncthreads();
  int ni = t & 63, cc = (t >> 6) << 4;  // each wave owns one 16-wide c-chunk
  unsigned ob[8];
#pragma unroll
  for (int j = 0; j < 8; ++j) {
    unsigned lo = (unsigned)__builtin_bit_cast(unsigned short, tile[cc + 2 * j][ni]);
    unsigned hi = (unsigned)__builtin_bit_cast(unsigned short, tile[cc + 2 * j + 1][ni]);
    ob[j] = lo | (hi << 16);
  }
  bf16_t* dst = xT + (size_t)(b * 4096 + n0 + ni) * 512 + c0 + cc;
  reinterpret_cast<u32x4*>(dst)[0] = *(u32x4*)&ob[0];
  reinterpret_cast<u32x4*>(dst)[1] = *(u32x4*)&ob[4];
}

// ---------------- K0b/K0c: f32 weights -> bf16 (optionally scale k-rows) -----------
// Scale for k-rows folds SCALE (1/8) AND log2(e) so attn can use exp2 directly.
__global__ __launch_bounds__(256) void k_convert_w(const float* __restrict__ w,
                                                   bf16_t* __restrict__ o, int do_scale) {
  int i = (blockIdx.x * 256 + threadIdx.x) * 4;
  float4 v = *reinterpret_cast<const float4*>(w + i);
  if (do_scale) {
    const float s = 0.125f * LOG2E;  // SCALE * log2e
    int m = i >> 9;  // row (512 cols per row)
    if (m >= 512 && m < 1024) { v.x *= s; v.y *= s; v.z *= s; v.w *= s; }
  }
  uint2 st; st.x = pack2(v.x, v.y); st.y = pack2(v.z, v.w);
  *reinterpret_cast<uint2*>(o + i) = st;
}

// ---------------- K1: qkv GEMM, LDS-staged: M=8192 N=1536 K=512 ---------------------
// BM=128 BN=128 BK=64; 512 thr (8 waves as 2x4, each 64x32 out). A/B tiles staged
// once per block per k-step (reg-staged, issue-early/write-late, dbuf, XOR-swizzle).
__global__ __launch_bounds__(512, 4) void k_qkv_gemm(const bf16_t* __restrict__ xT,
                                                     const bf16_t* __restrict__ wq,
                                                     bf16_t* __restrict__ Qn,
                                                     bf16_t* __restrict__ Katt,
                                                     bf16_t* __restrict__ Vbuf) {
  __shared__ bf16_t As[2][128 * 64];  // [buf][row*64 + slot*8], slot = gran ^ (row&7)
  __shared__ bf16_t Bs[2][128 * 64];
  int bid = blockIdx.x;  // 768
  int tm = bid / 12, tn = bid % 12;
  int tid = threadIdx.x;
  int lane = tid & 63, wave = tid >> 6;
  int n15 = lane & 15, g = lane >> 4;
  int wm = wave & 1, wn = wave >> 1;  // 2 x 4 wave grid
  int row0 = tm * 128, col0 = tn * 128;

  // staging map: thread -> (row srow & srow+64, slot sslot) of both A and B tiles
  int srow = tid >> 3, sslot = tid & 7;
  int sgran = sslot ^ (srow & 7);  // pre-swizzled source granule (rule #21)
  const bf16_t* Ag = xT + (size_t)(row0 + srow) * 512 + sgran * 8;
  const bf16_t* Bg = wq + (size_t)(col0 + srow) * 512 + sgran * 8;
  int sdst = srow * 64 + sslot * 8;

  u32x4 ra0 = *reinterpret_cast<const u32x4*>(Ag);
  u32x4 ra1 = *reinterpret_cast<const u32x4*>(Ag + 64 * 512);
  u32x4 rb0 = *reinterpret_cast<const u32x4*>(Bg);
  u32x4 rb1 = *reinterpret_cast<const u32x4*>(Bg + 64 * 512);
  *reinterpret_cast<u32x4*>(&As[0][sdst]) = ra0;
  *reinterpret_cast<u32x4*>(&As[0][sdst + 4096]) = ra1;
  *reinterpret_cast<u32x4*>(&Bs[0][sdst]) = rb0;
  *reinterpret_cast<u32x4*>(&Bs[0][sdst + 4096]) = rb1;
  __syncthreads();

  f32x4 acc[4][2] = {};
  int cur = 0;
  for (int step = 0; step < 8; ++step) {
    if (step < 7) {  // issue next-tile loads early; hide under this step's compute
      int k0n = (step + 1) << 6;
      ra0 = *reinterpret_cast<const u32x4*>(Ag + k0n);
      ra1 = *reinterpret_cast<const u32x4*>(Ag + 64 * 512 + k0n);
      rb0 = *reinterpret_cast<const u32x4*>(Bg + k0n);
      rb1 = *reinterpret_cast<const u32x4*>(Bg + 64 * 512 + k0n);
    }
    const bf16_t* Al = As[cur];
    const bf16_t* Bl = Bs[cur];
#pragma unroll
    for (int kh = 0; kh < 2; ++kh) {
      bf16x8 a[4], b[2];
#pragma unroll
      for (int mf = 0; mf < 4; ++mf) {
        int r = wm * 64 + mf * 16 + n15;
        a[mf] = *reinterpret_cast<const bf16x8*>(Al + r * 64 + (((kh * 4 + g) ^ (r & 7)) << 3));
      }
#pragma unroll
      for (int nf = 0; nf < 2; ++nf) {
        int r = wn * 32 + nf * 16 + n15;
        b[nf] = *reinterpret_cast<const bf16x8*>(Bl + r * 64 + (((kh * 4 + g) ^ (r & 7)) << 3));
      }
#pragma unroll
      for (int mf = 0; mf < 4; ++mf)
#pragma unroll
        for (int nf = 0; nf < 2; ++nf) acc[mf][nf] = mfma16(a[mf], b[nf], acc[mf][nf]);
    }
    if (step < 7) {  // write-late into the other buffer; barrier publishes it
      *reinterpret_cast<u32x4*>(&As[cur ^ 1][sdst]) = ra0;
      *reinterpret_cast<u32x4*>(&As[cur ^ 1][sdst + 4096]) = ra1;
      *reinterpret_cast<u32x4*>(&Bs[cur ^ 1][sdst]) = rb0;
      *reinterpret_cast<u32x4*>(&Bs[cur ^ 1][sdst + 4096]) = rb1;
    }
    __syncthreads();
    cur ^= 1;
  }
  // epilogue: scatter into Qn/Katt/Vbuf as [bh][n][d]
  int t = col0 >> 9;  // 0:q 1:k(scaled via weights) 2:v — tile never crosses t
  bf16_t* dstbuf = (t == 0) ? Qn : (t == 1) ? Katt : Vbuf;
#pragma unroll
  for (int mf = 0; mf < 4; ++mf)
#pragma unroll
    for (int r = 0; r < 4; ++r) {
      int rgl = row0 + wm * 64 + mf * 16 + g * 4 + r;
      int b_ = rgl >> 12, n = rgl & 4095;
#pragma unroll
      for (int nf = 0; nf < 2; ++nf) {
        int col = col0 + wn * 32 + nf * 16 + n15;
        int h = (col >> 6) & 7, d = col & 63;
        dstbuf[(((size_t)(b_ * 8 + h) * 4096 + n) << 6) + d] = (bf16_t)acc[mf][nf][r];
      }
    }
}

// ---------------- K2: Qn[bh][n][d] -> QT[bh][d][n] (bf16 transpose) ----------------
__global__ __launch_bounds__(256) void k_transpose_q(const bf16_t* __restrict__ Qn,
                                                     bf16_t* __restrict__ QT) {
  __shared__ bf16_t tile[64][72];  // [n_local][d]
  int bid = blockIdx.x;            // 16 * 64
  int head = bid >> 6;
  int ntile = bid & 63;
  int n0 = ntile << 6;
  int t = threadIdx.x;
  int i = t >> 2, dc = (t & 3) << 4;
  const bf16_t* src = Qn + ((size_t)head * 4096 + n0 + i) * 64 + dc;
  *(u32x4*)&tile[i][dc] = reinterpret_cast<const u32x4*>(src)[0];
  *(u32x4*)&tile[i][dc + 8] = reinterpret_cast<const u32x4*>(src)[1];
  __syncthreads();
  int d = t & 63, nc2 = (t >> 6) << 4;
  unsigned ob[8];
#pragma unroll
  for (int j = 0; j < 8; ++j) {
    unsigned lo = (unsigned)__builtin_bit_cast(unsigned short, tile[nc2 + 2 * j][d]);
    unsigned hi = (unsigned)__builtin_bit_cast(unsigned short, tile[nc2 + 2 * j + 1][d]);
    ob[j] = lo | (hi << 16);
  }
  bf16_t* dst = QT + ((size_t)head * 64 + d) * 4096 + n0 + nc2;
  reinterpret_cast<u32x4*>(dst)[0] = *(u32x4*)&ob[0];
  reinterpret_cast<u32x4*>(dst)[1] = *(u32x4*)&ob[4];
}

// ---------------- K3: flash attention, LDS-staged V/Q, fixed-base softmax -----------
// (R11 winner — FROZEN)
__global__ __launch_bounds__(512, 4) void k_attn(const bf16_t* __restrict__ Katt,
                                                 const bf16_t* __restrict__ Vbuf,
                                                 const bf16_t* __restrict__ QT,
                                                 bf16_t* __restrict__ OT) {
  __shared__ bf16_t Vt[2][4096];       // [buf][m_row*64 + d]  (granule-swizzled)
  __shared__ bf16_t Qs[2][4096];       // [buf][d_row*64 + m]  (granule-swizzled)
  __shared__ bf16_t tlds[8][16][72];   // transpose staging
  int bid = blockIdx.x;   // 512
  int head = bid & 15;
  int ntile = bid >> 4;   // 0..31
  int tid = threadIdx.x;
  int wave = tid >> 6, lane = tid & 63;
  int n15 = lane & 15, g = lane >> 4;
  int nrow0 = ntile * 128 + wave * 16;

  const bf16_t* Kp = Katt + ((size_t)head * 4096 + nrow0 + n15) * 64 + g * 8;
  bf16x8 kf0 = *reinterpret_cast<const bf16x8*>(Kp);
  bf16x8 kf1 = *reinterpret_cast<const bf16x8*>(Kp + 32);

  int vrow = tid >> 3, vg = tid & 7;
  int soff = vrow * 64 + ((vg ^ (vrow & 7)) << 3);
  const bf16_t* VgB = Vbuf + ((size_t)head * 4096 + vrow) * 64 + vg * 8;
  const bf16_t* QgB = QT + ((size_t)head * 64 + vrow) * 4096 + vg * 8;

  u32x4 vreg = *reinterpret_cast<const u32x4*>(VgB);
  u32x4 qreg = *reinterpret_cast<const u32x4*>(QgB);
  *reinterpret_cast<u32x4*>(&Vt[0][soff]) = vreg;
  *reinterpret_cast<u32x4*>(&Qs[0][soff]) = qreg;
  __syncthreads();

  f32x4 o[4] = {};
  float lacc = 0.f;
  bool hi_g = (g >= 2);
  int srcA = n15 + 16 * ((2 * g) & 3);
  int srcB = n15 + 16 * ((2 * g + 1) & 3);
  int sw = n15 & 7;
  int voff0 = n15 * 64 + (((g) ^ sw) << 3);
  int voff1 = n15 * 64 + (((g + 4) ^ sw) << 3);

  int cur = 0;
  for (int it = 0; it < 64; ++it) {
    if (it < 63) {
      vreg = *reinterpret_cast<const u32x4*>(VgB + (size_t)(it + 1) * 4096);
      qreg = *reinterpret_cast<const u32x4*>(QgB + (it + 1) * 64);
    }
    const bf16_t* Vl = Vt[cur];
    const bf16_t* Ql = Qs[cur];
    f32x4 p[4];
#pragma unroll
    for (int f = 0; f < 4; ++f) {
      bf16x8 av0 = *reinterpret_cast<const bf16x8*>(Vl + f * 1024 + voff0);
      bf16x8 av1 = *reinterpret_cast<const bf16x8*>(Vl + f * 1024 + voff1);
      f32x4 s = {};
      s = mfma16(av0, kf0, s);
      s = mfma16(av1, kf1, s);
      p[f] = s;
    }
    unsigned pk[4][2];
#pragma unroll
    for (int f = 0; f < 4; ++f) {
#pragma unroll
      for (int r = 0; r < 4; ++r) {
        float e = __builtin_amdgcn_exp2f(p[f][r]);
        p[f][r] = e;
        lacc += e;
      }
      pk[f][0] = pack2(p[f][0], p[f][1]);
      pk[f][1] = pack2(p[f][2], p[f][3]);
    }
    bf16x8 aP[2];
#pragma unroll
    for (int kk = 0; kk < 2; ++kk) {
      unsigned t00a = (unsigned)__shfl((int)pk[2 * kk + 0][0], srcA);
      unsigned t01a = (unsigned)__shfl((int)pk[2 * kk + 0][1], srcA);
      unsigned t10a = (unsigned)__shfl((int)pk[2 * kk + 1][0], srcA);
      unsigned t11a = (unsigned)__shfl((int)pk[2 * kk + 1][1], srcA);
      unsigned t00b = (unsigned)__shfl((int)pk[2 * kk + 0][0], srcB);
      unsigned t01b = (unsigned)__shfl((int)pk[2 * kk + 0][1], srcB);
      unsigned t10b = (unsigned)__shfl((int)pk[2 * kk + 1][0], srcB);
      unsigned t11b = (unsigned)__shfl((int)pk[2 * kk + 1][1], srcB);
      u32x4 uu;
      uu[0] = hi_g ? t10a : t00a;
      uu[1] = hi_g ? t11a : t01a;
      uu[2] = hi_g ? t10b : t00b;
      uu[3] = hi_g ? t11b : t01b;
      aP[kk] = __builtin_bit_cast(bf16x8, uu);
    }
#pragma unroll
    for (int db = 0; db < 4; ++db) {
      bf16x8 bq0 = *reinterpret_cast<const bf16x8*>(Ql + db * 1024 + voff0);
      bf16x8 bq1 = *reinterpret_cast<const bf16x8*>(Ql + db * 1024 + voff1);
      o[db] = mfma16(aP[0], bq0, o[db]);
      o[db] = mfma16(aP[1], bq1, o[db]);
    }
    if (it < 63) {
      *reinterpret_cast<u32x4*>(&Vt[cur ^ 1][soff]) = vreg;
      *reinterpret_cast<u32x4*>(&Qs[cur ^ 1][soff]) = qreg;
    }
    __syncthreads();
    cur ^= 1;
  }

  lacc += __shfl_xor(lacc, 16);
  lacc += __shfl_xor(lacc, 32);
#pragma unroll
  for (int r = 0; r < 4; ++r) {
    float l_r = __shfl(lacc, (g << 2) | r);
    float inv = 1.0f / l_r;
#pragma unroll
    for (int db = 0; db < 4; ++db)
      tlds[wave][g * 4 + r][n15 + 16 * db] = (bf16_t)(o[db][r] * inv);
  }
  __syncthreads();
  {
    int d = lane;
    unsigned ob[8];
#pragma unroll
    for (int j = 0; j < 8; ++j) {
      unsigned lo = (unsigned)__builtin_bit_cast(unsigned short, tlds[wave][2 * j][d]);
      unsigned hi = (unsigned)__builtin_bit_cast(unsigned short, tlds[wave][2 * j + 1][d]);
      ob[j] = lo | (hi << 16);
    }
    bf16_t* dst = OT + ((size_t)head * 64 + d) * 4096 + (size_t)ntile * 128 + wave * 16;
    reinterpret_cast<u32x4*>(dst)[0] = *(u32x4*)&ob[0];
    reinterpret_cast<u32x4*>(dst)[1] = *(u32x4*)&ob[4];
  }
}

// ---------------- K4: proj GEMM, LDS-staged: M=8192 N=512 K=512, + bias -------------
__global__ __launch_bounds__(512, 4) void k_proj_gemm(const bf16_t* __restrict__ Y,
                                                      const bf16_t* __restrict__ wp,
                                                      const float* __restrict__ bp,
                                                      float* __restrict__ out) {
  __shared__ bf16_t As[2][128 * 64];
  __shared__ bf16_t Bs[2][128 * 64];
  int bid = blockIdx.x;  // 256
  int tm = bid >> 2, tn = bid & 3;
  int tid = threadIdx.x;
  int lane = tid & 63, wave = tid >> 6;
  int n15 = lane & 15, g = lane >> 4;
  int wm = wave & 1, wn = wave >> 1;
  int row0 = tm * 128, col0 = tn * 128;

  int srow = tid >> 3, sslot = tid & 7;
  int sgran = sslot ^ (srow & 7);
  const bf16_t* Ag = Y + (size_t)(row0 + srow) * 512 + sgran * 8;
  const bf16_t* Bg = wp + (size_t)(col0 + srow) * 512 + sgran * 8;
  int sdst = srow * 64 + sslot * 8;

  u32x4 ra0 = *reinterpret_cast<const u32x4*>(Ag);
  u32x4 ra1 = *reinterpret_cast<const u32x4*>(Ag + 64 * 512);
  u32x4 rb0 = *reinterpret_cast<const u32x4*>(Bg);
  u32x4 rb1 = *reinterpret_cast<const u32x4*>(Bg + 64 * 512);
  *reinterpret_cast<u32x4*>(&As[0][sdst]) = ra0;
  *reinterpret_cast<u32x4*>(&As[0][sdst + 4096]) = ra1;
  *reinterpret_cast<u32x4*>(&Bs[0][sdst]) = rb0;
  *reinterpret_cast<u32x4*>(&Bs[0][sdst + 4096]) = rb1;
  __syncthreads();

  f32x4 acc[4][2] = {};
  int cur = 0;
  for (int step = 0; step < 8; ++step) {
    if (step < 7) {
      int k0n = (step + 1) << 6;
      ra0 = *reinterpret_cast<const u32x4*>(Ag + k0n);
      ra1 = *reinterpret_cast<const u32x4*>(Ag + 64 * 512 + k0n);
      rb0 = *reinterpret_cast<const u32x4*>(Bg + k0n);
      rb1 = *reinterpret_cast<const u32x4*>(Bg + 64 * 512 + k0n);
    }
    const bf16_t* Al = As[cur];
    const bf16_t* Bl = Bs[cur];
#pragma unroll
    for (int kh = 0; kh < 2; ++kh) {
      bf16x8 a[4], b[2];
#pragma unroll
      for (int mf = 0; mf < 4; ++mf) {
        int r = wm * 64 + mf * 16 + n15;
        a[mf] = *reinterpret_cast<const bf16x8*>(Al + r * 64 + (((kh * 4 + g) ^ (r & 7)) << 3));
      }
#pragma unroll
      for (int nf = 0; nf < 2; ++nf) {
        int r = wn * 32 + nf * 16 + n15;
        b[nf] = *reinterpret_cast<const bf16x8*>(Bl + r * 64 + (((kh * 4 + g) ^ (r & 7)) << 3));
      }
#pragma unroll
      for (int mf = 0; mf < 4; ++mf)
#pragma unroll
        for (int nf = 0; nf < 2; ++nf) acc[mf][nf] = mfma16(a[mf], b[nf], acc[mf][nf]);
    }
    if (step < 7) {
      *reinterpret_cast<u32x4*>(&As[cur ^ 1][sdst]) = ra0;
      *reinterpret_cast<u32x4*>(&As[cur ^ 1][sdst + 4096]) = ra1;
      *reinterpret_cast<u32x4*>(&Bs[cur ^ 1][sdst]) = rb0;
      *reinterpret_cast<u32x4*>(&Bs[cur ^ 1][sdst + 4096]) = rb1;
    }
    __syncthreads();
    cur ^= 1;
  }
  float bias[2];
#pragma unroll
  for (int nf = 0; nf < 2; ++nf) bias[nf] = bp[col0 + wn * 32 + nf * 16 + n15];
#pragma unroll
  for (int mf = 0; mf < 4; ++mf)
#pragma unroll
    for (int r = 0; r < 4; ++r) {
      int rgl = row0 + wm * 64 + mf * 16 + g * 4 + r;
#pragma unroll
      for (int nf = 0; nf < 2; ++nf) {
        int col = col0 + wn * 32 + nf * 16 + n15;
        out[(size_t)rgl * 512 + col] = acc[mf][nf][r] + bias[nf];
      }
    }
}

// ---------------- launch -------------------------------------------------------------
extern "C" void kernel_launch(void* const* d_in, const int* in_sizes, int n_in,
                              void* d_out, int out_size, void* d_ws, size_t ws_size,
                              hipStream_t stream) {
  const float* x      = (const float*)d_in[0];
  const float* w_qkv  = (const float*)d_in[1];
  const float* w_proj = (const float*)d_in[2];
  const float* b_proj = (const float*)d_in[3];
  float* out = (float*)d_out;
  char* ws = (char*)d_ws;

  // workspace map (bytes), 34 MB total:
  //   [0, 8M)        xT   (dead after K1)  -> reused as QT by K2
  //   [8M, 9.5M)     wqkv
  //   [9.5M, 10M)    wproj
  //   [10M, 18M)     Qn   (dead after K2)  -> reused as OT by K3
  //   [18M, 26M)     Katt
  //   [26M, 34M)     Vbuf
  bf16_t* xT    = (bf16_t*)(ws + 0);
  bf16_t* wqkv  = (bf16_t*)(ws + 8388608);
  bf16_t* wproj = (bf16_t*)(ws + 9961472);
  bf16_t* Qn    = (bf16_t*)(ws + 10485760);
  bf16_t* Katt  = (bf16_t*)(ws + 18874368);
  bf16_t* Vbuf  = (bf16_t*)(ws + 27262976);
  bf16_t* QT    = (bf16_t*)(ws + 0);          // over xT
  bf16_t* OT    = (bf16_t*)(ws + 10485760);   // over Qn

  k_transpose_x<<<dim3(1024), dim3(256), 0, stream>>>(x, xT);
  k_convert_w<<<dim3(768), dim3(256), 0, stream>>>(w_qkv, wqkv, 1);
  k_convert_w<<<dim3(256), dim3(256), 0, stream>>>(w_proj, wproj, 0);
  k_qkv_gemm<<<dim3(768), dim3(512), 0, stream>>>(xT, wqkv, Qn, Katt, Vbuf);
  k_transpose_q<<<dim3(1024), dim3(256), 0, stream>>>(Qn, QT);
  k_attn<<<dim3(512), dim3(512), 0, stream>>>(Katt, Vbuf, QT, OT);
  k_proj_gemm<<<dim3(256), dim3(512), 0, stream>>>(OT, wproj, b_proj, out);
}

// Round 14
// 220.263 us; speedup vs baseline: 2.7839x; 1.0855x over previous
//
#include <hip/hip_runtime.h>
#include <hip/hip_bf16.h>
#include <cstdint>

// ChannelAttention: x(2,512,64,64) f32, w_qkv(1536,512), w_proj(512,512), b_proj(512)
// Pipeline: xT(bf16) -> qkv GEMM (q written transposed) -> flash attn -> OT[b,h,d,n]
//           -> flat OT == scrambled Y matrix -> proj GEMM + bias -> d_out f32.
// R14: (1) k_transpose_q folded into k_qkv_gemm's epilogue (LDS transpose of the
//      q-tiles, coalesced QT write) — one fewer kernel + gap. (2) s_setprio(1)
//      around k_attn MFMA clusters (T5, proven on attn). All else frozen at R13.

typedef __bf16 bf16_t;
typedef __bf16 bf16x8 __attribute__((ext_vector_type(8)));
typedef float f32x4 __attribute__((ext_vector_type(4)));
typedef unsigned int u32x4 __attribute__((ext_vector_type(4)));

#define DEVFN static __device__ __forceinline__
#define LOG2E 1.4426950408889634f

DEVFN f32x4 mfma16(bf16x8 a, bf16x8 b, f32x4 c) {
  return __builtin_amdgcn_mfma_f32_16x16x32_bf16(a, b, c, 0, 0, 0);
}
DEVFN unsigned bfbits(float x) { return (unsigned)__builtin_bit_cast(unsigned short, (bf16_t)x); }
DEVFN unsigned pack2(float lo, float hi) { return bfbits(lo) | (bfbits(hi) << 16); }

// ---------------- K0a: x (2,512,4096) f32 -> xT (8192,512) bf16 (transpose+cast) ----
__global__ __launch_bounds__(256) void k_transpose_x(const float* __restrict__ x,
                                                     bf16_t* __restrict__ xT) {
  __shared__ bf16_t tile[64][72];  // [c_local][n_local], padded
  int bid = blockIdx.x;            // 2 * 8 * 64 = 1024
  int ntile = bid & 63;
  int ctile = (bid >> 6) & 7;
  int b = bid >> 9;
  int n0 = ntile << 6, c0 = ctile << 6;
  int t = threadIdx.x;
  int ci = t >> 2, nc = (t & 3) << 4;
  const float4* src4 = reinterpret_cast<const float4*>(
      x + (size_t)(b * 512 + c0 + ci) * 4096 + n0 + nc);
#pragma unroll
  for (int j4 = 0; j4 < 4; ++j4) {
    float4 v = src4[j4];
    tile[ci][nc + j4 * 4 + 0] = (bf16_t)v.x;
    tile[ci][nc + j4 * 4 + 1] = (bf16_t)v.y;
    tile[ci][nc + j4 * 4 + 2] = (bf16_t)v.z;
    tile[ci][nc + j4 * 4 + 3] = (bf16_t)v.w;
  }
  __syncthreads();
  int ni = t & 63, cc = (t >> 6) << 4;  // each wave owns one 16-wide c-chunk
  unsigned ob[8];
#pragma unroll
  for (int j = 0; j < 8; ++j) {
    unsigned lo = (unsigned)__builtin_bit_cast(unsigned short, tile[cc + 2 * j][ni]);
    unsigned hi = (unsigned)__builtin_bit_cast(unsigned short, tile[cc + 2 * j + 1][ni]);
    ob[j] = lo | (hi << 16);
  }
  bf16_t* dst = xT + (size_t)(b * 4096 + n0 + ni) * 512 + c0 + cc;
  reinterpret_cast<u32x4*>(dst)[0] = *(u32x4*)&ob[0];
  reinterpret_cast<u32x4*>(dst)[1] = *(u32x4*)&ob[4];
}

// ---------------- K0b/K0c: f32 weights -> bf16 (optionally scale k-rows) -----------
// Scale for k-rows folds SCALE (1/8) AND log2(e) so attn can use exp2 directly.
__global__ __launch_bounds__(256) void k_convert_w(const float* __restrict__ w,
                                                   bf16_t* __restrict__ o, int do_scale) {
  int i = (blockIdx.x * 256 + threadIdx.x) * 4;
  float4 v = *reinterpret_cast<const float4*>(w + i);
  if (do_scale) {
    const float s = 0.125f * LOG2E;  // SCALE * log2e
    int m = i >> 9;  // row (512 cols per row)
    if (m >= 512 && m < 1024) { v.x *= s; v.y *= s; v.z *= s; v.w *= s; }
  }
  uint2 st; st.x = pack2(v.x, v.y); st.y = pack2(v.z, v.w);
  *reinterpret_cast<uint2*>(o + i) = st;
}

// ---------------- K1: qkv GEMM, LDS-staged: M=8192 N=1536 K=512 ---------------------
// BM=128 BN=128 BK=64; 512 thr (8 waves as 2x4, each 64x32 out). A/B tiles staged
// once per block per k-step (reg-staged, issue-early/write-late, dbuf, XOR-swizzle).
// q-tiles (t==0) are transposed in LDS and written straight to QT[bh][d][n].
__global__ __launch_bounds__(512, 4) void k_qkv_gemm(const bf16_t* __restrict__ xT,
                                                     const bf16_t* __restrict__ wq,
                                                     bf16_t* __restrict__ QT,
                                                     bf16_t* __restrict__ Katt,
                                                     bf16_t* __restrict__ Vbuf) {
  __shared__ bf16_t smem[32768];  // 64KB: As=[0,16384) Bs=[16384,32768); epilogue T
#define AsP(b) (smem + (b) * 8192)
#define BsP(b) (smem + 16384 + (b) * 8192)
  int bid = blockIdx.x;  // 768
  int tm = bid / 12, tn = bid % 12;
  int tid = threadIdx.x;
  int lane = tid & 63, wave = tid >> 6;
  int n15 = lane & 15, g = lane >> 4;
  int wm = wave & 1, wn = wave >> 1;  // 2 x 4 wave grid
  int row0 = tm * 128, col0 = tn * 128;

  // staging map: thread -> (row srow & srow+64, slot sslot) of both A and B tiles
  int srow = tid >> 3, sslot = tid & 7;
  int sgran = sslot ^ (srow & 7);  // pre-swizzled source granule (rule #21)
  const bf16_t* Ag = xT + (size_t)(row0 + srow) * 512 + sgran * 8;
  const bf16_t* Bg = wq + (size_t)(col0 + srow) * 512 + sgran * 8;
  int sdst = srow * 64 + sslot * 8;

  u32x4 ra0 = *reinterpret_cast<const u32x4*>(Ag);
  u32x4 ra1 = *reinterpret_cast<const u32x4*>(Ag + 64 * 512);
  u32x4 rb0 = *reinterpret_cast<const u32x4*>(Bg);
  u32x4 rb1 = *reinterpret_cast<const u32x4*>(Bg + 64 * 512);
  *reinterpret_cast<u32x4*>(AsP(0) + sdst) = ra0;
  *reinterpret_cast<u32x4*>(AsP(0) + sdst + 4096) = ra1;
  *reinterpret_cast<u32x4*>(BsP(0) + sdst) = rb0;
  *reinterpret_cast<u32x4*>(BsP(0) + sdst + 4096) = rb1;
  __syncthreads();

  f32x4 acc[4][2] = {};
  int cur = 0;
  for (int step = 0; step < 8; ++step) {
    if (step < 7) {  // issue next-tile loads early; hide under this step's compute
      int k0n = (step + 1) << 6;
      ra0 = *reinterpret_cast<const u32x4*>(Ag + k0n);
      ra1 = *reinterpret_cast<const u32x4*>(Ag + 64 * 512 + k0n);
      rb0 = *reinterpret_cast<const u32x4*>(Bg + k0n);
      rb1 = *reinterpret_cast<const u32x4*>(Bg + 64 * 512 + k0n);
    }
    const bf16_t* Al = AsP(cur);
    const bf16_t* Bl = BsP(cur);
#pragma unroll
    for (int kh = 0; kh < 2; ++kh) {
      bf16x8 a[4], b[2];
#pragma unroll
      for (int mf = 0; mf < 4; ++mf) {
        int r = wm * 64 + mf * 16 + n15;
        a[mf] = *reinterpret_cast<const bf16x8*>(Al + r * 64 + (((kh * 4 + g) ^ (r & 7)) << 3));
      }
#pragma unroll
      for (int nf = 0; nf < 2; ++nf) {
        int r = wn * 32 + nf * 16 + n15;
        b[nf] = *reinterpret_cast<const bf16x8*>(Bl + r * 64 + (((kh * 4 + g) ^ (r & 7)) << 3));
      }
#pragma unroll
      for (int mf = 0; mf < 4; ++mf)
#pragma unroll
        for (int nf = 0; nf < 2; ++nf) acc[mf][nf] = mfma16(a[mf], b[nf], acc[mf][nf]);
    }
    if (step < 7) {  // write-late into the other buffer; barrier publishes it
      *reinterpret_cast<u32x4*>(AsP(cur ^ 1) + sdst) = ra0;
      *reinterpret_cast<u32x4*>(AsP(cur ^ 1) + sdst + 4096) = ra1;
      *reinterpret_cast<u32x4*>(BsP(cur ^ 1) + sdst) = rb0;
      *reinterpret_cast<u32x4*>(BsP(cur ^ 1) + sdst + 4096) = rb1;
    }
    __syncthreads();
    cur ^= 1;
  }
  int t = col0 >> 9;  // 0:q 1:k(scaled via weights) 2:v — tile never crosses t
  if (t == 0) {
    // q: transpose via LDS (T[col][row], pad 136 -> 272B rows, 16B-aligned reads,
    // <=2-way banks) and write QT[bh][d][n] coalesced. Replaces k_transpose_q.
    bf16_t* T = smem;  // 128*136 = 17408 elems <= 32768
#pragma unroll
    for (int mf = 0; mf < 4; ++mf)
#pragma unroll
      for (int r = 0; r < 4; ++r) {
        int rl = wm * 64 + mf * 16 + g * 4 + r;
#pragma unroll
        for (int nf = 0; nf < 2; ++nf) {
          int cl = wn * 32 + nf * 16 + n15;
          T[cl * 136 + rl] = (bf16_t)acc[mf][nf][r];
        }
      }
    __syncthreads();
    int cr = tid >> 2, nch = (tid & 3) << 5;
    int b_ = row0 >> 12, n0 = row0 & 4095;
    int head = (col0 + cr) >> 6, d = cr & 63;
    bf16_t* dst = QT + (((size_t)(b_ * 8 + head) * 64 + d) << 12) + n0 + nch;
    const bf16_t* srcT = T + cr * 136 + nch;
#pragma unroll
    for (int j = 0; j < 4; ++j)
      reinterpret_cast<u32x4*>(dst)[j] = *reinterpret_cast<const u32x4*>(srcT + j * 8);
  } else {
    bf16_t* dstbuf = (t == 1) ? Katt : Vbuf;
#pragma unroll
    for (int mf = 0; mf < 4; ++mf)
#pragma unroll
      for (int r = 0; r < 4; ++r) {
        int rgl = row0 + wm * 64 + mf * 16 + g * 4 + r;
        int b_ = rgl >> 12, n = rgl & 4095;
#pragma unroll
        for (int nf = 0; nf < 2; ++nf) {
          int col = col0 + wn * 32 + nf * 16 + n15;
          int h = (col >> 6) & 7, d = col & 63;
          dstbuf[(((size_t)(b_ * 8 + h) * 4096 + n) << 6) + d] = (bf16_t)acc[mf][nf][r];
        }
      }
  }
#undef AsP
#undef BsP
}

// ---------------- K3: flash attention, LDS-staged V/Q, fixed-base softmax -----------
// (R11 winner + T5 setprio around MFMA clusters)
__global__ __launch_bounds__(512, 4) void k_attn(const bf16_t* __restrict__ Katt,
                                                 const bf16_t* __restrict__ Vbuf,
                                                 const bf16_t* __restrict__ QT,
                                                 bf16_t* __restrict__ OT) {
  __shared__ bf16_t Vt[2][4096];       // [buf][m_row*64 + d]  (granule-swizzled)
  __shared__ bf16_t Qs[2][4096];       // [buf][d_row*64 + m]  (granule-swizzled)
  __shared__ bf16_t tlds[8][16][72];   // transpose staging
  int bid = blockIdx.x;   // 512
  int head = bid & 15;
  int ntile = bid >> 4;   // 0..31
  int tid = threadIdx.x;
  int wave = tid >> 6, lane = tid & 63;
  int n15 = lane & 15, g = lane >> 4;
  int nrow0 = ntile * 128 + wave * 16;

  const bf16_t* Kp = Katt + ((size_t)head * 4096 + nrow0 + n15) * 64 + g * 8;
  bf16x8 kf0 = *reinterpret_cast<const bf16x8*>(Kp);
  bf16x8 kf1 = *reinterpret_cast<const bf16x8*>(Kp + 32);

  int vrow = tid >> 3, vg = tid & 7;
  int soff = vrow * 64 + ((vg ^ (vrow & 7)) << 3);
  const bf16_t* VgB = Vbuf + ((size_t)head * 4096 + vrow) * 64 + vg * 8;
  const bf16_t* QgB = QT + ((size_t)head * 64 + vrow) * 4096 + vg * 8;

  u32x4 vreg = *reinterpret_cast<const u32x4*>(VgB);
  u32x4 qreg = *reinterpret_cast<const u32x4*>(QgB);
  *reinterpret_cast<u32x4*>(&Vt[0][soff]) = vreg;
  *reinterpret_cast<u32x4*>(&Qs[0][soff]) = qreg;
  __syncthreads();

  f32x4 o[4] = {};
  float lacc = 0.f;
  bool hi_g = (g >= 2);
  int srcA = n15 + 16 * ((2 * g) & 3);
  int srcB = n15 + 16 * ((2 * g + 1) & 3);
  int sw = n15 & 7;
  int voff0 = n15 * 64 + (((g) ^ sw) << 3);
  int voff1 = n15 * 64 + (((g + 4) ^ sw) << 3);

  int cur = 0;
  for (int it = 0; it < 64; ++it) {
    if (it < 63) {
      vreg = *reinterpret_cast<const u32x4*>(VgB + (size_t)(it + 1) * 4096);
      qreg = *reinterpret_cast<const u32x4*>(QgB + (it + 1) * 64);
    }
    const bf16_t* Vl = Vt[cur];
    const bf16_t* Ql = Qs[cur];
    f32x4 p[4];
    __builtin_amdgcn_s_setprio(1);
#pragma unroll
    for (int f = 0; f < 4; ++f) {
      bf16x8 av0 = *reinterpret_cast<const bf16x8*>(Vl + f * 1024 + voff0);
      bf16x8 av1 = *reinterpret_cast<const bf16x8*>(Vl + f * 1024 + voff1);
      f32x4 s = {};
      s = mfma16(av0, kf0, s);
      s = mfma16(av1, kf1, s);
      p[f] = s;
    }
    __builtin_amdgcn_s_setprio(0);
    unsigned pk[4][2];
#pragma unroll
    for (int f = 0; f < 4; ++f) {
#pragma unroll
      for (int r = 0; r < 4; ++r) {
        float e = __builtin_amdgcn_exp2f(p[f][r]);
        p[f][r] = e;
        lacc += e;
      }
      pk[f][0] = pack2(p[f][0], p[f][1]);
      pk[f][1] = pack2(p[f][2], p[f][3]);
    }
    bf16x8 aP[2];
#pragma unroll
    for (int kk = 0; kk < 2; ++kk) {
      unsigned t00a = (unsigned)__shfl((int)pk[2 * kk + 0][0], srcA);
      unsigned t01a = (unsigned)__shfl((int)pk[2 * kk + 0][1], srcA);
      unsigned t10a = (unsigned)__shfl((int)pk[2 * kk + 1][0], srcA);
      unsigned t11a = (unsigned)__shfl((int)pk[2 * kk + 1][1], srcA);
      unsigned t00b = (unsigned)__shfl((int)pk[2 * kk + 0][0], srcB);
      unsigned t01b = (unsigned)__shfl((int)pk[2 * kk + 0][1], srcB);
      unsigned t10b = (unsigned)__shfl((int)pk[2 * kk + 1][0], srcB);
      unsigned t11b = (unsigned)__shfl((int)pk[2 * kk + 1][1], srcB);
      u32x4 uu;
      uu[0] = hi_g ? t10a : t00a;
      uu[1] = hi_g ? t11a : t01a;
      uu[2] = hi_g ? t10b : t00b;
      uu[3] = hi_g ? t11b : t01b;
      aP[kk] = __builtin_bit_cast(bf16x8, uu);
    }
    __builtin_amdgcn_s_setprio(1);
#pragma unroll
    for (int db = 0; db < 4; ++db) {
      bf16x8 bq0 = *reinterpret_cast<const bf16x8*>(Ql + db * 1024 + voff0);
      bf16x8 bq1 = *reinterpret_cast<const bf16x8*>(Ql + db * 1024 + voff1);
      o[db] = mfma16(aP[0], bq0, o[db]);
      o[db] = mfma16(aP[1], bq1, o[db]);
    }
    __builtin_amdgcn_s_setprio(0);
    if (it < 63) {
      *reinterpret_cast<u32x4*>(&Vt[cur ^ 1][soff]) = vreg;
      *reinterpret_cast<u32x4*>(&Qs[cur ^ 1][soff]) = qreg;
    }
    __syncthreads();
    cur ^= 1;
  }

  lacc += __shfl_xor(lacc, 16);
  lacc += __shfl_xor(lacc, 32);
#pragma unroll
  for (int r = 0; r < 4; ++r) {
    float l_r = __shfl(lacc, (g << 2) | r);
    float inv = 1.0f / l_r;
#pragma unroll
    for (int db = 0; db < 4; ++db)
      tlds[wave][g * 4 + r][n15 + 16 * db] = (bf16_t)(o[db][r] * inv);
  }
  __syncthreads();
  {
    int d = lane;
    unsigned ob[8];
#pragma unroll
    for (int j = 0; j < 8; ++j) {
      unsigned lo = (unsigned)__builtin_bit_cast(unsigned short, tlds[wave][2 * j][d]);
      unsigned hi = (unsigned)__builtin_bit_cast(unsigned short, tlds[wave][2 * j + 1][d]);
      ob[j] = lo | (hi << 16);
    }
    bf16_t* dst = OT + ((size_t)head * 64 + d) * 4096 + (size_t)ntile * 128 + wave * 16;
    reinterpret_cast<u32x4*>(dst)[0] = *(u32x4*)&ob[0];
    reinterpret_cast<u32x4*>(dst)[1] = *(u32x4*)&ob[4];
  }
}

// ---------------- K4: proj GEMM, LDS-staged: M=8192 N=512 K=512, + bias -------------
__global__ __launch_bounds__(512, 4) void k_proj_gemm(const bf16_t* __restrict__ Y,
                                                      const bf16_t* __restrict__ wp,
                                                      const float* __restrict__ bp,
                                                      float* __restrict__ out) {
  __shared__ bf16_t As[2][128 * 64];
  __shared__ bf16_t Bs[2][128 * 64];
  int bid = blockIdx.x;  // 256
  int tm = bid >> 2, tn = bid & 3;
  int tid = threadIdx.x;
  int lane = tid & 63, wave = tid >> 6;
  int n15 = lane & 15, g = lane >> 4;
  int wm = wave & 1, wn = wave >> 1;
  int row0 = tm * 128, col0 = tn * 128;

  int srow = tid >> 3, sslot = tid & 7;
  int sgran = sslot ^ (srow & 7);
  const bf16_t* Ag = Y + (size_t)(row0 + srow) * 512 + sgran * 8;
  const bf16_t* Bg = wp + (size_t)(col0 + srow) * 512 + sgran * 8;
  int sdst = srow * 64 + sslot * 8;

  u32x4 ra0 = *reinterpret_cast<const u32x4*>(Ag);
  u32x4 ra1 = *reinterpret_cast<const u32x4*>(Ag + 64 * 512);
  u32x4 rb0 = *reinterpret_cast<const u32x4*>(Bg);
  u32x4 rb1 = *reinterpret_cast<const u32x4*>(Bg + 64 * 512);
  *reinterpret_cast<u32x4*>(&As[0][sdst]) = ra0;
  *reinterpret_cast<u32x4*>(&As[0][sdst + 4096]) = ra1;
  *reinterpret_cast<u32x4*>(&Bs[0][sdst]) = rb0;
  *reinterpret_cast<u32x4*>(&Bs[0][sdst + 4096]) = rb1;
  __syncthreads();

  f32x4 acc[4][2] = {};
  int cur = 0;
  for (int step = 0; step < 8; ++step) {
    if (step < 7) {
      int k0n = (step + 1) << 6;
      ra0 = *reinterpret_cast<const u32x4*>(Ag + k0n);
      ra1 = *reinterpret_cast<const u32x4*>(Ag + 64 * 512 + k0n);
      rb0 = *reinterpret_cast<const u32x4*>(Bg + k0n);
      rb1 = *reinterpret_cast<const u32x4*>(Bg + 64 * 512 + k0n);
    }
    const bf16_t* Al = As[cur];
    const bf16_t* Bl = Bs[cur];
#pragma unroll
    for (int kh = 0; kh < 2; ++kh) {
      bf16x8 a[4], b[2];
#pragma unroll
      for (int mf = 0; mf < 4; ++mf) {
        int r = wm * 64 + mf * 16 + n15;
        a[mf] = *reinterpret_cast<const bf16x8*>(Al + r * 64 + (((kh * 4 + g) ^ (r & 7)) << 3));
      }
#pragma unroll
      for (int nf = 0; nf < 2; ++nf) {
        int r = wn * 32 + nf * 16 + n15;
        b[nf] = *reinterpret_cast<const bf16x8*>(Bl + r * 64 + (((kh * 4 + g) ^ (r & 7)) << 3));
      }
#pragma unroll
      for (int mf = 0; mf < 4; ++mf)
#pragma unroll
        for (int nf = 0; nf < 2; ++nf) acc[mf][nf] = mfma16(a[mf], b[nf], acc[mf][nf]);
    }
    if (step < 7) {
      *reinterpret_cast<u32x4*>(&As[cur ^ 1][sdst]) = ra0;
      *reinterpret_cast<u32x4*>(&As[cur ^ 1][sdst + 4096]) = ra1;
      *reinterpret_cast<u32x4*>(&Bs[cur ^ 1][sdst]) = rb0;
      *reinterpret_cast<u32x4*>(&Bs[cur ^ 1][sdst + 4096]) = rb1;
    }
    __syncthreads();
    cur ^= 1;
  }
  float bias[2];
#pragma unroll
  for (int nf = 0; nf < 2; ++nf) bias[nf] = bp[col0 + wn * 32 + nf * 16 + n15];
#pragma unroll
  for (int mf = 0; mf < 4; ++mf)
#pragma unroll
    for (int r = 0; r < 4; ++r) {
      int rgl = row0 + wm * 64 + mf * 16 + g * 4 + r;
#pragma unroll
      for (int nf = 0; nf < 2; ++nf) {
        int col = col0 + wn * 32 + nf * 16 + n15;
        out[(size_t)rgl * 512 + col] = acc[mf][nf][r] + bias[nf];
      }
    }
}

// ---------------- launch -------------------------------------------------------------
extern "C" void kernel_launch(void* const* d_in, const int* in_sizes, int n_in,
                              void* d_out, int out_size, void* d_ws, size_t ws_size,
                              hipStream_t stream) {
  const float* x      = (const float*)d_in[0];
  const float* w_qkv  = (const float*)d_in[1];
  const float* w_proj = (const float*)d_in[2];
  const float* b_proj = (const float*)d_in[3];
  float* out = (float*)d_out;
  char* ws = (char*)d_ws;

  // workspace map (bytes), 34 MB total:
  //   [0, 8M)        xT   (dead after K1)  -> reused as OT by K3
  //   [8M, 9.5M)     wqkv
  //   [9.5M, 10M)    wproj
  //   [10M, 18M)     QT   (written directly by K1's q-epilogue)
  //   [18M, 26M)     Katt
  //   [26M, 34M)     Vbuf
  bf16_t* xT    = (bf16_t*)(ws + 0);
  bf16_t* wqkv  = (bf16_t*)(ws + 8388608);
  bf16_t* wproj = (bf16_t*)(ws + 9961472);
  bf16_t* QT    = (bf16_t*)(ws + 10485760);
  bf16_t* Katt  = (bf16_t*)(ws + 18874368);
  bf16_t* Vbuf  = (bf16_t*)(ws + 27262976);
  bf16_t* OT    = (bf16_t*)(ws + 0);          // over xT (dead after K1)

  k_transpose_x<<<dim3(1024), dim3(256), 0, stream>>>(x, xT);
  k_convert_w<<<dim3(768), dim3(256), 0, stream>>>(w_qkv, wqkv, 1);
  k_convert_w<<<dim3(256), dim3(256), 0, stream>>>(w_proj, wproj, 0);
  k_qkv_gemm<<<dim3(768), dim3(512), 0, stream>>>(xT, wqkv, QT, Katt, Vbuf);
  k_attn<<<dim3(512), dim3(512), 0, stream>>>(Katt, Vbuf, QT, OT);
  k_proj_gemm<<<dim3(256), dim3(512), 0, stream>>>(OT, wproj, b_proj, out);
}